// Round 2
// baseline (358.817 us; speedup 1.0000x reference)
//
#include <hip/hip_runtime.h>

#define SEQ  2048
#define HID  128
#define NB   32
#define TILE 32            // output rows per block
#define ROWS 40            // staged rows: s0-3 .. s0+34 meaningful (38), padded to 40
#define HSTR 132           // LDS row stride in floats (128+4: 16B-aligned, conflict-safe)

// ---------------------------------------------------------------------------
// Fully fused: enc1 -> enc2 -> gc1 -> gc2 -> gc3 -> pool, one block per
// (32-row seq tile, batch). All inter-layer tensors live in LDS; the 3-wide
// halo makes the three tridiagonal aggregations local to the block.
// 256 threads: tx = tid&31 (4 cols at tx*4), ty = tid>>5 (5 rows at ty*5).
// ---------------------------------------------------------------------------
__global__ __launch_bounds__(256, 3) void fused_kernel(
    const float* __restrict__ x,
    const float* __restrict__ enc_w1, const float* __restrict__ enc_b1,
    const float* __restrict__ enc_w2, const float* __restrict__ enc_b2,
    const float* __restrict__ gc1_w, const float* __restrict__ gc1_b,
    const float* __restrict__ gc2_w, const float* __restrict__ gc2_b,
    const float* __restrict__ gc3_w, const float* __restrict__ gc3_b,
    float* __restrict__ pooled)
{
  __shared__ __align__(16) float hbuf[ROWS * HSTR];   // 21120 B: layer activations
  __shared__ __align__(16) float ubuf[ROWS * HSTR];   // 21120 B: union {xs+w1s | Ws slice | tbuf}
  __shared__ float bsh[HID];
  __shared__ float psum[256];

  const int tid = threadIdx.x;
  const int tx4 = (tid & 31) * 4;     // col base
  const int ty5 = (tid >> 5) * 5;     // row base
  const int s0  = blockIdx.x * TILE;
  const int b   = blockIdx.y;

  // ---------------- stage x, enc_w1, enc_b1 ----------------
  float* xs  = ubuf;            // [ROWS][6]
  float* w1s = ubuf + 512;      // [6][128]
  for (int f = tid; f < ROWS * 6; f += 256) {
    const int m = f / 6, c = f - m * 6;
    const int s = s0 - 3 + m;
    xs[f] = (s >= 0 && s < SEQ && m < 38)
              ? x[((long long)b * SEQ + s) * 6 + c] : 0.f;
  }
  for (int f = tid; f < 6 * HID; f += 256) w1s[f] = enc_w1[f];
  if (tid < HID) bsh[tid] = enc_b1[tid];
  __syncthreads();

  // ---------------- enc1: h1 = relu(x @ w1 + b1) -> hbuf ----------------
  {
    float acc[5][4];
    #pragma unroll
    for (int i = 0; i < 5; ++i)
      acc[i][0] = acc[i][1] = acc[i][2] = acc[i][3] = 0.f;
    #pragma unroll
    for (int k = 0; k < 6; ++k) {
      const float4 w = *(const float4*)&w1s[k * HID + tx4];
      #pragma unroll
      for (int i = 0; i < 5; ++i) {
        const float a = xs[(ty5 + i) * 6 + k];
        acc[i][0] = fmaf(a, w.x, acc[i][0]);
        acc[i][1] = fmaf(a, w.y, acc[i][1]);
        acc[i][2] = fmaf(a, w.z, acc[i][2]);
        acc[i][3] = fmaf(a, w.w, acc[i][3]);
      }
    }
    const float4 bb = *(const float4*)&bsh[tx4];
    #pragma unroll
    for (int i = 0; i < 5; ++i) {
      float4 o;
      o.x = fmaxf(acc[i][0] + bb.x, 0.f);
      o.y = fmaxf(acc[i][1] + bb.y, 0.f);
      o.z = fmaxf(acc[i][2] + bb.z, 0.f);
      o.w = fmaxf(acc[i][3] + bb.w, 0.f);
      *(float4*)&hbuf[(ty5 + i) * HSTR + tx4] = o;
    }
  }
  // visibility of hbuf + release of xs/w1s handled by kb0 barrier below

  // ---------------- 4 x (128-K GEMM [+ tridiag agg + relu]) ----------------
  for (int L = 0; L < 4; ++L) {
    const float* __restrict__ Wg = (L == 0) ? enc_w2 : (L == 1) ? gc1_w
                                 : (L == 2) ? gc2_w  : gc3_w;
    const float* __restrict__ bg = (L == 0) ? enc_b2 : (L == 1) ? gc1_b
                                 : (L == 2) ? gc2_b  : gc3_b;

    float acc[5][4];
    #pragma unroll
    for (int i = 0; i < 5; ++i)
      acc[i][0] = acc[i][1] = acc[i][2] = acc[i][3] = 0.f;

    // register prefetch of W slice kb=0 (hides L2 latency across barrier)
    float4 pre[4];
    #pragma unroll
    for (int q = 0; q < 4; ++q) pre[q] = ((const float4*)Wg)[q * 256 + tid];

    for (int kb = 0; kb < 4; ++kb) {
      __syncthreads();                       // prior ubuf readers done
      #pragma unroll
      for (int q = 0; q < 4; ++q) ((float4*)ubuf)[q * 256 + tid] = pre[q];
      if (kb == 0 && tid < HID) bsh[tid] = bg[tid];
      if (kb < 3) {
        #pragma unroll
        for (int q = 0; q < 4; ++q)
          pre[q] = ((const float4*)Wg)[(kb + 1) * 1024 + q * 256 + tid];
      }
      __syncthreads();

      const int kbase = kb * 32;
      #pragma unroll
      for (int k4 = 0; k4 < 8; ++k4) {
        const float4 w0 = *(const float4*)&ubuf[(k4 * 4 + 0) * HID + tx4];
        const float4 w1 = *(const float4*)&ubuf[(k4 * 4 + 1) * HID + tx4];
        const float4 w2 = *(const float4*)&ubuf[(k4 * 4 + 2) * HID + tx4];
        const float4 w3 = *(const float4*)&ubuf[(k4 * 4 + 3) * HID + tx4];
        #pragma unroll
        for (int i = 0; i < 5; ++i) {
          const float4 a = *(const float4*)&hbuf[(ty5 + i) * HSTR + kbase + k4 * 4];
          acc[i][0] = fmaf(a.x, w0.x, acc[i][0]);
          acc[i][1] = fmaf(a.x, w0.y, acc[i][1]);
          acc[i][2] = fmaf(a.x, w0.z, acc[i][2]);
          acc[i][3] = fmaf(a.x, w0.w, acc[i][3]);
          acc[i][0] = fmaf(a.y, w1.x, acc[i][0]);
          acc[i][1] = fmaf(a.y, w1.y, acc[i][1]);
          acc[i][2] = fmaf(a.y, w1.z, acc[i][2]);
          acc[i][3] = fmaf(a.y, w1.w, acc[i][3]);
          acc[i][0] = fmaf(a.z, w2.x, acc[i][0]);
          acc[i][1] = fmaf(a.z, w2.y, acc[i][1]);
          acc[i][2] = fmaf(a.z, w2.z, acc[i][2]);
          acc[i][3] = fmaf(a.z, w2.w, acc[i][3]);
          acc[i][0] = fmaf(a.w, w3.x, acc[i][0]);
          acc[i][1] = fmaf(a.w, w3.y, acc[i][1]);
          acc[i][2] = fmaf(a.w, w3.z, acc[i][2]);
          acc[i][3] = fmaf(a.w, w3.w, acc[i][3]);
        }
      }
    }
    __syncthreads();   // GEMM's ubuf(Ws) + hbuf reads complete

    if (L == 0) {
      // enc2 epilogue: h = acc + b2 (no relu) -> hbuf
      const float4 bb = *(const float4*)&bsh[tx4];
      #pragma unroll
      for (int i = 0; i < 5; ++i) {
        float4 o;
        o.x = acc[i][0] + bb.x;  o.y = acc[i][1] + bb.y;
        o.z = acc[i][2] + bb.z;  o.w = acc[i][3] + bb.w;
        *(float4*)&hbuf[(ty5 + i) * HSTR + tx4] = o;
      }
    } else {
      // gc epilogue: t = acc + b (zero outside the sequence) -> ubuf
      const float4 bb = *(const float4*)&bsh[tx4];
      #pragma unroll
      for (int i = 0; i < 5; ++i) {
        const int m = ty5 + i;
        const int s = s0 - 3 + m;
        const bool v = (s >= 0 && s < SEQ);
        float4 o;
        o.x = v ? acc[i][0] + bb.x : 0.f;
        o.y = v ? acc[i][1] + bb.y : 0.f;
        o.z = v ? acc[i][2] + bb.z : 0.f;
        o.w = v ? acc[i][3] + bb.w : 0.f;
        *(float4*)&ubuf[m * HSTR + tx4] = o;
      }
      __syncthreads();
      // tridiagonal aggregate + relu -> hbuf (flat 1-elem mapping, stride-1)
      #pragma unroll
      for (int i = 0; i < 20; ++i) {
        const int f = i * 256 + tid;
        const int m = f >> 7, c = f & 127;
        const int mm = (m == 0) ? 0 : m - 1;
        const int mp = (m == ROWS - 1) ? ROWS - 1 : m + 1;
        const float sum = ubuf[mm * HSTR + c] + ubuf[m * HSTR + c] + ubuf[mp * HSTR + c];
        const int s = s0 - 3 + m;
        const float invd = (s == 0 || s == SEQ - 1) ? (1.0f / (2.0f + 1e-8f))
                                                    : (1.0f / (3.0f + 1e-8f));
        hbuf[m * HSTR + c] = fmaxf(sum * invd, 0.f);
      }
      // next kb0 barrier (or pool barrier) orders hbuf writes vs readers
    }
  }

  // ---------------- pool: sum the 32 owned rows (m = 3..34) ----------------
  __syncthreads();
  {
    const int g = tid >> 7, c = tid & 127;
    float a = 0.f;
    #pragma unroll
    for (int r = 0; r < 16; ++r) a += hbuf[(3 + g * 16 + r) * HSTR + c];
    psum[tid] = a;
    __syncthreads();
    if (tid < HID) atomicAdd(&pooled[b * HID + tid], psum[tid] + psum[tid + HID]);
  }
}

// ---------------------------------------------------------------------------
// Classifier: out = relu(mean @ w1 + b1) @ w2 + b2, one block per batch row
// ---------------------------------------------------------------------------
__global__ __launch_bounds__(64) void cls_kernel(
    const float* __restrict__ pooled,
    const float* __restrict__ w1, const float* __restrict__ b1,
    const float* __restrict__ w2, const float* __restrict__ b2,
    float* __restrict__ out)
{
  __shared__ float ms[128];
  __shared__ float hid[64];
  const int b = blockIdx.x, tid = threadIdx.x;
  ms[tid] = pooled[b * 128 + tid] * (1.0f / 2048.0f);
  ms[tid + 64] = pooled[b * 128 + 64 + tid] * (1.0f / 2048.0f);
  __syncthreads();
  float a = b1[tid];
  for (int k = 0; k < 128; ++k) a = fmaf(ms[k], w1[k * 64 + tid], a);
  hid[tid] = a > 0.f ? a : 0.f;
  __syncthreads();
  if (tid < 3) {
    float o = b2[tid];
    for (int k = 0; k < 64; ++k) o = fmaf(hid[k], w2[k * 3 + tid], o);
    out[b * 3 + tid] = o;
  }
}

extern "C" void kernel_launch(void* const* d_in, const int* in_sizes, int n_in,
                              void* d_out, int out_size, void* d_ws, size_t ws_size,
                              hipStream_t stream) {
  (void)in_sizes; (void)n_in; (void)out_size; (void)ws_size;
  const float* x      = (const float*)d_in[0];
  const float* enc_w1 = (const float*)d_in[1];
  const float* enc_b1 = (const float*)d_in[2];
  const float* enc_w2 = (const float*)d_in[3];
  const float* enc_b2 = (const float*)d_in[4];
  const float* gc1_w  = (const float*)d_in[5];
  const float* gc1_b  = (const float*)d_in[6];
  const float* gc2_w  = (const float*)d_in[7];
  const float* gc2_b  = (const float*)d_in[8];
  const float* gc3_w  = (const float*)d_in[9];
  const float* gc3_b  = (const float*)d_in[10];
  const float* cls_w1 = (const float*)d_in[11];
  const float* cls_b1 = (const float*)d_in[12];
  const float* cls_w2 = (const float*)d_in[13];
  const float* cls_b2 = (const float*)d_in[14];

  float* pooled = (float*)d_ws;
  hipMemsetAsync(pooled, 0, NB * HID * sizeof(float), stream);

  fused_kernel<<<dim3(SEQ / TILE, NB), 256, 0, stream>>>(
      x, enc_w1, enc_b1, enc_w2, enc_b2,
      gc1_w, gc1_b, gc2_w, gc2_b, gc3_w, gc3_b, pooled);
  cls_kernel<<<dim3(NB), 64, 0, stream>>>(pooled, cls_w1, cls_b1, cls_w2, cls_b2,
                                          (float*)d_out);
}